// Round 1
// baseline (719388.867 us; speedup 1.0000x reference)
//
#include <hip/hip_runtime.h>
#include <hip/hip_cooperative_groups.h>

namespace cg = cooperative_groups;

#define HDIM  1024
#define FOURH 4096
#define TSEQ  2048
#define NCLS  512

// ---------------------------------------------------------------------------
// GEMM: C[M,N] = A[M,K] * B[N,K]^T + bias1[N] (+ bias2[N] if non-null)
// 64x64 tile, 256 threads, k-major LDS with ds_read_b128 fragment loads.
// ---------------------------------------------------------------------------
__global__ __launch_bounds__(256) void gemm_bias_kernel(
    const float* __restrict__ A, const float* __restrict__ B,
    const float* __restrict__ bias1, const float* __restrict__ bias2,
    float* __restrict__ C, int M, int N, int K)
{
    __shared__ float As[16][68];   // [k][row], pad 68 to spread banks
    __shared__ float Bs[16][68];   // [k][col]

    const int tid = threadIdx.x;
    const int tx = tid & 15;       // 16 col-groups
    const int ty = tid >> 4;       // 16 row-groups
    const int n0 = blockIdx.x * 64;
    const int m0 = blockIdx.y * 64;
    const int r  = tid >> 2;       // 0..63 row/col to load
    const int kq = tid & 3;        // which float4 along K

    float acc[4][4];
#pragma unroll
    for (int i = 0; i < 4; ++i)
#pragma unroll
        for (int j = 0; j < 4; ++j) acc[i][j] = 0.f;

    for (int k0 = 0; k0 < K; k0 += 16) {
        float4 va = *(const float4*)&A[(size_t)(m0 + r) * K + k0 + 4 * kq];
        float4 vb = *(const float4*)&B[(size_t)(n0 + r) * K + k0 + 4 * kq];
        As[4 * kq + 0][r] = va.x; As[4 * kq + 1][r] = va.y;
        As[4 * kq + 2][r] = va.z; As[4 * kq + 3][r] = va.w;
        Bs[4 * kq + 0][r] = vb.x; Bs[4 * kq + 1][r] = vb.y;
        Bs[4 * kq + 2][r] = vb.z; Bs[4 * kq + 3][r] = vb.w;
        __syncthreads();
#pragma unroll
        for (int kk = 0; kk < 16; ++kk) {
            float4 a = *(const float4*)&As[kk][4 * ty];
            float4 b = *(const float4*)&Bs[kk][4 * tx];
            acc[0][0] = fmaf(a.x, b.x, acc[0][0]);
            acc[0][1] = fmaf(a.x, b.y, acc[0][1]);
            acc[0][2] = fmaf(a.x, b.z, acc[0][2]);
            acc[0][3] = fmaf(a.x, b.w, acc[0][3]);
            acc[1][0] = fmaf(a.y, b.x, acc[1][0]);
            acc[1][1] = fmaf(a.y, b.y, acc[1][1]);
            acc[1][2] = fmaf(a.y, b.z, acc[1][2]);
            acc[1][3] = fmaf(a.y, b.w, acc[1][3]);
            acc[2][0] = fmaf(a.z, b.x, acc[2][0]);
            acc[2][1] = fmaf(a.z, b.y, acc[2][1]);
            acc[2][2] = fmaf(a.z, b.z, acc[2][2]);
            acc[2][3] = fmaf(a.z, b.w, acc[2][3]);
            acc[3][0] = fmaf(a.w, b.x, acc[3][0]);
            acc[3][1] = fmaf(a.w, b.y, acc[3][1]);
            acc[3][2] = fmaf(a.w, b.z, acc[3][2]);
            acc[3][3] = fmaf(a.w, b.w, acc[3][3]);
        }
        __syncthreads();
    }

    float4 bv = *(const float4*)&bias1[n0 + 4 * tx];
    if (bias2) {
        float4 b2 = *(const float4*)&bias2[n0 + 4 * tx];
        bv.x += b2.x; bv.y += b2.y; bv.z += b2.z; bv.w += b2.w;
    }
#pragma unroll
    for (int i = 0; i < 4; ++i) {
        const int row = m0 + 4 * ty + i;
        float4 o;
        o.x = acc[i][0] + bv.x;
        o.y = acc[i][1] + bv.y;
        o.z = acc[i][2] + bv.z;
        o.w = acc[i][3] + bv.w;
        *(float4*)&C[(size_t)row * N + n0 + 4 * tx] = o;
    }
}

// ---------------------------------------------------------------------------
// Persistent LSTM scan: 512 blocks x 512 threads (2 blocks/CU), cooperative.
// Block b owns hidden units {2b, 2b+1}: 8 rows of W_hh kept in LDS for the
// whole sequence. One grid.sync() per timestep.
// ---------------------------------------------------------------------------
__global__ __launch_bounds__(512, 4) void lstm_scan_kernel(
    const float* __restrict__ gx,    // [TSEQ, 4H] input contribution + biases
    const float* __restrict__ Whh,   // [4H, H]
    float* __restrict__ h_out,       // [TSEQ, H]
    float* __restrict__ hbuf)        // [H] scratch: current h
{
    __shared__ float shW[8][HDIM];   // 8 rows of W_hh (32 KB)
    __shared__ float sh_h[HDIM];     // current h (4 KB)
    __shared__ float sh_gate[8];

    cg::grid_group grid = cg::this_grid();

    const int tid  = threadIdx.x;
    const int b    = blockIdx.x;       // 0..511
    const int w    = tid >> 6;         // wave 0..7
    const int lane = tid & 63;
    const int g    = w >> 1;           // gate 0..3 (i,f,g,o)
    const int u    = w & 1;            // unit-within-block
    const int row  = g * HDIM + 2 * b + u;  // W_hh / gx row for this wave

    // Preload this block's 8 weight rows into LDS (once).
    for (int w2 = 0; w2 < 8; ++w2) {
        const int rr = (w2 >> 1) * HDIM + 2 * b + (w2 & 1);
        for (int k = tid; k < HDIM; k += 512)
            shW[w2][k] = Whh[(size_t)rr * HDIM + k];
    }
    for (int k = tid; k < HDIM; k += 512) sh_h[k] = 0.f;
    float c = 0.f;                     // cell state, live in threads 0..1
    __syncthreads();

    // Prefetch gx for t=0.
    float gxv = (lane == 0) ? gx[row] : 0.f;

    for (int t = 0; t < TSEQ; ++t) {
        // 1024-dot for this wave's gate row.
        float acc = 0.f;
#pragma unroll
        for (int kk = 0; kk < 16; ++kk)
            acc = fmaf(shW[w][lane + 64 * kk], sh_h[lane + 64 * kk], acc);
#pragma unroll
        for (int off = 32; off; off >>= 1)
            acc += __shfl_xor(acc, off, 64);
        if (lane == 0) sh_gate[w] = acc + gxv;
        __syncthreads();

        if (tid < 2) {
            const int un = 2 * b + tid;
            const float gi = sh_gate[0 + tid];
            const float gf = sh_gate[2 + tid];
            const float gg = sh_gate[4 + tid];
            const float go = sh_gate[6 + tid];
            const float si = 1.f / (1.f + __expf(-gi));
            const float sf = 1.f / (1.f + __expf(-gf));
            const float tg = tanhf(gg);
            const float so = 1.f / (1.f + __expf(-go));
            c = sf * c + si * tg;
            const float h = so * tanhf(c);
            hbuf[un] = h;
            h_out[(size_t)t * HDIM + un] = h;
        }

        // Prefetch next step's gx while we wait on the barrier.
        if (lane == 0 && t + 1 < TSEQ)
            gxv = gx[(size_t)(t + 1) * FOURH + row];

        __threadfence();
        grid.sync();

        if (t + 1 < TSEQ) {
            const float2* hb2 = (const float2*)hbuf;
            const float2 v = hb2[tid];
            sh_h[2 * tid]     = v.x;
            sh_h[2 * tid + 1] = v.y;
            __syncthreads();
        }
    }
}

// ---------------------------------------------------------------------------
extern "C" void kernel_launch(void* const* d_in, const int* in_sizes, int n_in,
                              void* d_out, int out_size, void* d_ws, size_t ws_size,
                              hipStream_t stream)
{
    (void)in_sizes; (void)n_in; (void)out_size; (void)ws_size;

    const float* x = (const float*)d_in[0];
    const float* W_ih[3] = {(const float*)d_in[1], (const float*)d_in[5], (const float*)d_in[9]};
    const float* W_hh[3] = {(const float*)d_in[2], (const float*)d_in[6], (const float*)d_in[10]};
    const float* b_ih[3] = {(const float*)d_in[3], (const float*)d_in[7], (const float*)d_in[11]};
    const float* b_hh[3] = {(const float*)d_in[4], (const float*)d_in[8], (const float*)d_in[12]};
    const float* fc_w = (const float*)d_in[13];
    const float* fc_b = (const float*)d_in[14];
    float* out = (float*)d_out;

    // Workspace layout (floats): gx[T*4H] | hA[T*H] | hB[T*H] | hbuf[H]
    float* gx   = (float*)d_ws;
    float* hA   = gx + (size_t)TSEQ * FOURH;
    float* hB   = hA + (size_t)TSEQ * HDIM;
    float* hbuf = hB + (size_t)TSEQ * HDIM;

    float* houts[3] = {hA, hB, hA};   // hA reusable after gx1 consumes it
    const float* in_seq = x;

    for (int l = 0; l < 3; ++l) {
        dim3 gg(FOURH / 64, TSEQ / 64);
        gemm_bias_kernel<<<gg, 256, 0, stream>>>(in_seq, W_ih[l], b_ih[l], b_hh[l],
                                                 gx, TSEQ, FOURH, HDIM);

        const float* gx_c  = gx;
        const float* whh_c = W_hh[l];
        float* ho          = houts[l];
        float* hb          = hbuf;
        void* args[] = {(void*)&gx_c, (void*)&whh_c, (void*)&ho, (void*)&hb};
        hipLaunchCooperativeKernel((void*)lstm_scan_kernel, dim3(512), dim3(512),
                                   args, 0, stream);
        in_seq = houts[l];
    }

    dim3 gf(NCLS / 64, TSEQ / 64);
    gemm_bias_kernel<<<gf, 256, 0, stream>>>(hA, fc_w, fc_b, nullptr,
                                             out, TSEQ, NCLS, HDIM);
}

// Round 2
// 93185.150 us; speedup vs baseline: 7.7200x; 7.7200x over previous
//
#include <hip/hip_runtime.h>

#define HDIM  1024
#define FOURH 4096
#define TSEQ  2048
#define NCLS  512

#define NBLK  512     // scan blocks
#define NGRP  16      // barrier groups
#define GRPSZ 32      // blocks per group (NBLK/NGRP)
#define UNITS 2       // hidden units per block
#define ROWS  8       // W_hh rows per block (4 gates x UNITS)

// barrier layout in uints: grp[g] at g*64, root at 1024, epoch at 1088
#define BAR_ROOT  1024
#define BAR_EPOCH 1088
#define BAR_BYTES 8192

// ---------------------------------------------------------------------------
// GEMM: C[M,N] = A[M,K] * B[N,K]^T + bias1[N] (+ bias2[N] if non-null)
// ---------------------------------------------------------------------------
__global__ __launch_bounds__(256) void gemm_bias_kernel(
    const float* __restrict__ A, const float* __restrict__ B,
    const float* __restrict__ bias1, const float* __restrict__ bias2,
    float* __restrict__ C, int M, int N, int K)
{
    __shared__ float As[16][68];
    __shared__ float Bs[16][68];

    const int tid = threadIdx.x;
    const int tx = tid & 15;
    const int ty = tid >> 4;
    const int n0 = blockIdx.x * 64;
    const int m0 = blockIdx.y * 64;
    const int r  = tid >> 2;
    const int kq = tid & 3;

    float acc[4][4];
#pragma unroll
    for (int i = 0; i < 4; ++i)
#pragma unroll
        for (int j = 0; j < 4; ++j) acc[i][j] = 0.f;

    for (int k0 = 0; k0 < K; k0 += 16) {
        float4 va = *(const float4*)&A[(size_t)(m0 + r) * K + k0 + 4 * kq];
        float4 vb = *(const float4*)&B[(size_t)(n0 + r) * K + k0 + 4 * kq];
        As[4 * kq + 0][r] = va.x; As[4 * kq + 1][r] = va.y;
        As[4 * kq + 2][r] = va.z; As[4 * kq + 3][r] = va.w;
        Bs[4 * kq + 0][r] = vb.x; Bs[4 * kq + 1][r] = vb.y;
        Bs[4 * kq + 2][r] = vb.z; Bs[4 * kq + 3][r] = vb.w;
        __syncthreads();
#pragma unroll
        for (int kk = 0; kk < 16; ++kk) {
            float4 a = *(const float4*)&As[kk][4 * ty];
            float4 b = *(const float4*)&Bs[kk][4 * tx];
            acc[0][0] = fmaf(a.x, b.x, acc[0][0]);
            acc[0][1] = fmaf(a.x, b.y, acc[0][1]);
            acc[0][2] = fmaf(a.x, b.z, acc[0][2]);
            acc[0][3] = fmaf(a.x, b.w, acc[0][3]);
            acc[1][0] = fmaf(a.y, b.x, acc[1][0]);
            acc[1][1] = fmaf(a.y, b.y, acc[1][1]);
            acc[1][2] = fmaf(a.y, b.z, acc[1][2]);
            acc[1][3] = fmaf(a.y, b.w, acc[1][3]);
            acc[2][0] = fmaf(a.z, b.x, acc[2][0]);
            acc[2][1] = fmaf(a.z, b.y, acc[2][1]);
            acc[2][2] = fmaf(a.z, b.z, acc[2][2]);
            acc[2][3] = fmaf(a.z, b.w, acc[2][3]);
            acc[3][0] = fmaf(a.w, b.x, acc[3][0]);
            acc[3][1] = fmaf(a.w, b.y, acc[3][1]);
            acc[3][2] = fmaf(a.w, b.z, acc[3][2]);
            acc[3][3] = fmaf(a.w, b.w, acc[3][3]);
        }
        __syncthreads();
    }

    float4 bv = *(const float4*)&bias1[n0 + 4 * tx];
    if (bias2) {
        float4 b2 = *(const float4*)&bias2[n0 + 4 * tx];
        bv.x += b2.x; bv.y += b2.y; bv.z += b2.z; bv.w += b2.w;
    }
#pragma unroll
    for (int i = 0; i < 4; ++i) {
        const int row = m0 + 4 * ty + i;
        float4 o;
        o.x = acc[i][0] + bv.x;
        o.y = acc[i][1] + bv.y;
        o.z = acc[i][2] + bv.z;
        o.w = acc[i][3] + bv.w;
        *(float4*)&C[(size_t)row * N + n0 + 4 * tx] = o;
    }
}

// ---------------------------------------------------------------------------
// Persistent LSTM scan. 512 blocks x 256 threads, cooperative (co-residency
// guarantee only; sync is a hand-rolled monotonic 2-level counter barrier).
// Block b owns hidden units {2b, 2b+1}; 8 rows of W_hh live in LDS.
// hbuf is double-buffered by t&1 (race fix vs cg version).
// ---------------------------------------------------------------------------
__global__ __launch_bounds__(256) void lstm_scan_kernel(
    const float* __restrict__ gx,    // [TSEQ, 4H] input contribution + biases
    const float* __restrict__ Whh,   // [4H, H]
    float* __restrict__ h_out,       // [TSEQ, H]
    float* __restrict__ hbuf,        // [2, H] double-buffered h exchange
    unsigned* __restrict__ bar,      // barrier counters (memset 0 per launch)
    int ebase)                       // epoch base = layer * TSEQ
{
    __shared__ __align__(16) float shW[ROWS][HDIM];   // 32 KB
    __shared__ __align__(16) float sh_h[HDIM];        // 4 KB
    __shared__ float sh_gate[4][UNITS];

    const int tid  = threadIdx.x;
    const int b    = blockIdx.x;
    const int w    = tid >> 6;         // wave 0..3 = gate
    const int lane = tid & 63;
    const int u0   = UNITS * b;        // first hidden unit owned

    // Preload 8 weight rows: row lr = gate(lr>>1), unit offset (lr&1).
#pragma unroll
    for (int lr = 0; lr < ROWS; ++lr) {
        const int gr = (lr >> 1) * HDIM + u0 + (lr & 1);
        *(float4*)&shW[lr][4 * tid] = *(const float4*)&Whh[(size_t)gr * HDIM + 4 * tid];
    }
    {
        float4 z; z.x = z.y = z.z = z.w = 0.f;
        *(float4*)&sh_h[4 * tid] = z;                  // h0 = 0
    }
    float c = 0.f;                                     // cell state (wave0 lanes 0..1)
    __syncthreads();

    // gx for t=0: wave0 lanes 0..7 hold (gate=lane>>1, unit=lane&1).
    float gxv = 0.f;
    if (w == 0 && lane < 8)
        gxv = gx[(size_t)(lane >> 1) * HDIM + u0 + (lane & 1)];

    for (int t = 0; t < TSEQ; ++t) {
        // ---- dots: wave w computes gate w for its 2 units ----
        float4 hv[4];
#pragma unroll
        for (int j = 0; j < 4; ++j)
            hv[j] = *(const float4*)&sh_h[256 * j + 4 * lane];
#pragma unroll
        for (int u = 0; u < UNITS; ++u) {
            const float* Wr = shW[w * UNITS + u];
            float acc = 0.f;
#pragma unroll
            for (int j = 0; j < 4; ++j) {
                float4 wv = *(const float4*)&Wr[256 * j + 4 * lane];
                acc = fmaf(wv.x, hv[j].x, acc);
                acc = fmaf(wv.y, hv[j].y, acc);
                acc = fmaf(wv.z, hv[j].z, acc);
                acc = fmaf(wv.w, hv[j].w, acc);
            }
#pragma unroll
            for (int off = 32; off; off >>= 1)
                acc += __shfl_xor(acc, off, 64);
            if (lane == 0) sh_gate[w][u] = acc;
        }
        __syncthreads();

        // ---- gate nonlinearity + state update: wave0 lanes 0..1 ----
        // gx values for this thread's unit, pulled cross-lane (all lanes exec shfl).
        const float g0 = __shfl(gxv, 0 + (lane & 1), 64);
        const float g1 = __shfl(gxv, 2 + (lane & 1), 64);
        const float g2 = __shfl(gxv, 4 + (lane & 1), 64);
        const float g3 = __shfl(gxv, 6 + (lane & 1), 64);
        if (w == 0 && lane < UNITS) {
            const float gi = sh_gate[0][lane] + g0;
            const float gf = sh_gate[1][lane] + g1;
            const float gg = sh_gate[2][lane] + g2;
            const float go = sh_gate[3][lane] + g3;
            const float si = 1.f / (1.f + __expf(-gi));
            const float sf = 1.f / (1.f + __expf(-gf));
            const float tg = tanhf(gg);
            const float so = 1.f / (1.f + __expf(-go));
            c = sf * c + si * tg;
            const float h = so * tanhf(c);
            // publish h at the coherence point (bypasses per-XCD L2)
            __hip_atomic_store(&hbuf[(t & 1) * HDIM + u0 + lane], h,
                               __ATOMIC_RELAXED, __HIP_MEMORY_SCOPE_AGENT);
            h_out[(size_t)t * HDIM + u0 + lane] = h;   // consumed by next kernel
        }
        // prefetch next step's gx (overlaps barrier wait)
        if (w == 0 && lane < 8) {
            const int tn = (t + 1 < TSEQ) ? t + 1 : t;
            gxv = gx[(size_t)tn * FOURH + (size_t)(lane >> 1) * HDIM + u0 + (lane & 1)];
        }

        // ---- monotonic 2-level barrier ----
        if (tid == 0) {
            const unsigned tgt = (unsigned)(ebase + t + 1);
            unsigned old = __hip_atomic_fetch_add(&bar[(b & (NGRP - 1)) * 64], 1u,
                                                  __ATOMIC_ACQ_REL, __HIP_MEMORY_SCOPE_AGENT);
            if (old + 1 == GRPSZ * tgt) {
                unsigned r = __hip_atomic_fetch_add(&bar[BAR_ROOT], 1u,
                                                    __ATOMIC_ACQ_REL, __HIP_MEMORY_SCOPE_AGENT);
                if (r + 1 == NGRP * tgt)
                    __hip_atomic_store(&bar[BAR_EPOCH], tgt,
                                       __ATOMIC_RELEASE, __HIP_MEMORY_SCOPE_AGENT);
            }
            while (__hip_atomic_load(&bar[BAR_EPOCH], __ATOMIC_RELAXED,
                                     __HIP_MEMORY_SCOPE_AGENT) < tgt)
                __builtin_amdgcn_s_sleep(2);
            (void)__hip_atomic_load(&bar[BAR_EPOCH], __ATOMIC_ACQUIRE,
                                    __HIP_MEMORY_SCOPE_AGENT);
        }
        __syncthreads();

        // ---- restage h for t+1 (reads slot t&1; writers of t+1 use other slot) ----
        if (t + 1 < TSEQ) {
            float* hb = hbuf + (t & 1) * HDIM;
            float4 v;
            v.x = __hip_atomic_load(&hb[4 * tid + 0], __ATOMIC_RELAXED, __HIP_MEMORY_SCOPE_AGENT);
            v.y = __hip_atomic_load(&hb[4 * tid + 1], __ATOMIC_RELAXED, __HIP_MEMORY_SCOPE_AGENT);
            v.z = __hip_atomic_load(&hb[4 * tid + 2], __ATOMIC_RELAXED, __HIP_MEMORY_SCOPE_AGENT);
            v.w = __hip_atomic_load(&hb[4 * tid + 3], __ATOMIC_RELAXED, __HIP_MEMORY_SCOPE_AGENT);
            *(float4*)&sh_h[4 * tid] = v;
            __syncthreads();
        }
    }
}

// ---------------------------------------------------------------------------
extern "C" void kernel_launch(void* const* d_in, const int* in_sizes, int n_in,
                              void* d_out, int out_size, void* d_ws, size_t ws_size,
                              hipStream_t stream)
{
    (void)in_sizes; (void)n_in; (void)out_size; (void)ws_size;

    const float* x = (const float*)d_in[0];
    const float* W_ih[3] = {(const float*)d_in[1], (const float*)d_in[5], (const float*)d_in[9]};
    const float* W_hh[3] = {(const float*)d_in[2], (const float*)d_in[6], (const float*)d_in[10]};
    const float* b_ih[3] = {(const float*)d_in[3], (const float*)d_in[7], (const float*)d_in[11]};
    const float* b_hh[3] = {(const float*)d_in[4], (const float*)d_in[8], (const float*)d_in[12]};
    const float* fc_w = (const float*)d_in[13];
    const float* fc_b = (const float*)d_in[14];
    float* out = (float*)d_out;

    // ws layout: bar[8KB] | gx[T*4H] | hA[T*H] | hB[T*H] | hbuf[2*H]
    unsigned* bar = (unsigned*)d_ws;
    float* gx   = (float*)d_ws + BAR_BYTES / 4;
    float* hA   = gx + (size_t)TSEQ * FOURH;
    float* hB   = hA + (size_t)TSEQ * HDIM;
    float* hbuf = hB + (size_t)TSEQ * HDIM;

    hipMemsetAsync(bar, 0, BAR_BYTES, stream);

    float* houts[3] = {hA, hB, hA};
    const float* in_seq = x;

    for (int l = 0; l < 3; ++l) {
        dim3 gg(FOURH / 64, TSEQ / 64);
        gemm_bias_kernel<<<gg, 256, 0, stream>>>(in_seq, W_ih[l], b_ih[l], b_hh[l],
                                                 gx, TSEQ, FOURH, HDIM);

        const float* gx_c  = gx;
        const float* whh_c = W_hh[l];
        float* ho          = houts[l];
        float* hb          = hbuf;
        unsigned* bar_c    = bar;
        int ebase          = l * TSEQ;
        void* args[] = {(void*)&gx_c, (void*)&whh_c, (void*)&ho, (void*)&hb,
                        (void*)&bar_c, (void*)&ebase};
        hipLaunchCooperativeKernel((void*)lstm_scan_kernel, dim3(NBLK), dim3(256),
                                   args, 0, stream);
        in_seq = houts[l];
    }

    dim3 gf(NCLS / 64, TSEQ / 64);
    gemm_bias_kernel<<<gf, 256, 0, stream>>>(hA, fc_w, fc_b, nullptr,
                                             out, TSEQ, NCLS, HDIM);
}

// Round 3
// 24026.344 us; speedup vs baseline: 29.9417x; 3.8785x over previous
//
#include <hip/hip_runtime.h>

#define HDIM  1024
#define FOURH 4096
#define TSEQ  2048
#define NCLS  512

#define NBLK  512     // scan blocks
#define UNITS 2       // hidden units per block
#define ROWS  8       // W_hh rows per block (4 gates x UNITS)

// 3-level barrier tree: 64 groups of 8 blocks -> 8 mids -> 1 root.
// All counters monotonic, all atomics RELAXED (no L2 inv/wb!).
// Layout in uints (each counter on its own 256B line):
//   group g: g*64 (g<64) | mid m: 4096+m*64 | root: 5120 | epoch: 5184
#define MID_OFF   4096
#define ROOT_OFF  5120
#define EPOCH_OFF 5184
#define BAR_BYTES 24576

// ---------------------------------------------------------------------------
// GEMM: C[M,N] = A[M,K] * B[N,K]^T + bias1[N] (+ bias2[N] if non-null)
// ---------------------------------------------------------------------------
__global__ __launch_bounds__(256) void gemm_bias_kernel(
    const float* __restrict__ A, const float* __restrict__ B,
    const float* __restrict__ bias1, const float* __restrict__ bias2,
    float* __restrict__ C, int M, int N, int K)
{
    __shared__ float As[16][68];
    __shared__ float Bs[16][68];

    const int tid = threadIdx.x;
    const int tx = tid & 15;
    const int ty = tid >> 4;
    const int n0 = blockIdx.x * 64;
    const int m0 = blockIdx.y * 64;
    const int r  = tid >> 2;
    const int kq = tid & 3;

    float acc[4][4];
#pragma unroll
    for (int i = 0; i < 4; ++i)
#pragma unroll
        for (int j = 0; j < 4; ++j) acc[i][j] = 0.f;

    for (int k0 = 0; k0 < K; k0 += 16) {
        float4 va = *(const float4*)&A[(size_t)(m0 + r) * K + k0 + 4 * kq];
        float4 vb = *(const float4*)&B[(size_t)(n0 + r) * K + k0 + 4 * kq];
        As[4 * kq + 0][r] = va.x; As[4 * kq + 1][r] = va.y;
        As[4 * kq + 2][r] = va.z; As[4 * kq + 3][r] = va.w;
        Bs[4 * kq + 0][r] = vb.x; Bs[4 * kq + 1][r] = vb.y;
        Bs[4 * kq + 2][r] = vb.z; Bs[4 * kq + 3][r] = vb.w;
        __syncthreads();
#pragma unroll
        for (int kk = 0; kk < 16; ++kk) {
            float4 a = *(const float4*)&As[kk][4 * ty];
            float4 b = *(const float4*)&Bs[kk][4 * tx];
            acc[0][0] = fmaf(a.x, b.x, acc[0][0]);
            acc[0][1] = fmaf(a.x, b.y, acc[0][1]);
            acc[0][2] = fmaf(a.x, b.z, acc[0][2]);
            acc[0][3] = fmaf(a.x, b.w, acc[0][3]);
            acc[1][0] = fmaf(a.y, b.x, acc[1][0]);
            acc[1][1] = fmaf(a.y, b.y, acc[1][1]);
            acc[1][2] = fmaf(a.y, b.z, acc[1][2]);
            acc[1][3] = fmaf(a.y, b.w, acc[1][3]);
            acc[2][0] = fmaf(a.z, b.x, acc[2][0]);
            acc[2][1] = fmaf(a.z, b.y, acc[2][1]);
            acc[2][2] = fmaf(a.z, b.z, acc[2][2]);
            acc[2][3] = fmaf(a.z, b.w, acc[2][3]);
            acc[3][0] = fmaf(a.w, b.x, acc[3][0]);
            acc[3][1] = fmaf(a.w, b.y, acc[3][1]);
            acc[3][2] = fmaf(a.w, b.z, acc[3][2]);
            acc[3][3] = fmaf(a.w, b.w, acc[3][3]);
        }
        __syncthreads();
    }

    float4 bv = *(const float4*)&bias1[n0 + 4 * tx];
    if (bias2) {
        float4 b2 = *(const float4*)&bias2[n0 + 4 * tx];
        bv.x += b2.x; bv.y += b2.y; bv.z += b2.z; bv.w += b2.w;
    }
#pragma unroll
    for (int i = 0; i < 4; ++i) {
        const int row = m0 + 4 * ty + i;
        float4 o;
        o.x = acc[i][0] + bv.x;
        o.y = acc[i][1] + bv.y;
        o.z = acc[i][2] + bv.z;
        o.w = acc[i][3] + bv.w;
        *(float4*)&C[(size_t)row * N + n0 + 4 * tx] = o;
    }
}

// ---------------------------------------------------------------------------
// Persistent LSTM scan. 512 blocks x 256 threads, cooperative launch for
// co-residency; sync = hand-rolled 3-level monotonic counter barrier with
// ALL-RELAXED atomics (no buffer_inv/buffer_wb on the critical path).
// Ordering: producer's `s_waitcnt vmcnt(0)` before its arrival RMW makes the
// h stores complete at the coherence point before the arrival is visible;
// the data-dependent RMW chain (group->mid->root->epoch) carries that to all
// pollers. hbuf double-buffered by t&1.
// ---------------------------------------------------------------------------
__global__ __launch_bounds__(256) void lstm_scan_kernel(
    const float* __restrict__ gx,    // [TSEQ, 4H] input contribution + biases
    const float* __restrict__ Whh,   // [4H, H]
    float* __restrict__ h_out,       // [TSEQ, H]
    float* __restrict__ hbuf,        // [2, H] double-buffered h exchange
    unsigned* __restrict__ bar,      // barrier counters (memset 0 per launch)
    int ebase)                       // epoch base = layer * TSEQ
{
    __shared__ __align__(16) float shW[ROWS][HDIM];   // 32 KB
    __shared__ __align__(16) float sh_h[HDIM];        // 4 KB
    __shared__ float sh_gate[4][UNITS];

    const int tid  = threadIdx.x;
    const int b    = blockIdx.x;
    const int w    = tid >> 6;         // wave 0..3 = gate
    const int lane = tid & 63;
    const int u0   = UNITS * b;        // first hidden unit owned

    // Preload 8 weight rows: row lr = gate(lr>>1), unit (lr&1).
#pragma unroll
    for (int lr = 0; lr < ROWS; ++lr) {
        const int gr = (lr >> 1) * HDIM + u0 + (lr & 1);
        *(float4*)&shW[lr][4 * tid] = *(const float4*)&Whh[(size_t)gr * HDIM + 4 * tid];
    }
    {
        float4 z; z.x = z.y = z.z = z.w = 0.f;
        *(float4*)&sh_h[4 * tid] = z;                  // h0 = 0
    }
    float c = 0.f;                                     // cell state (wave0 lanes 0..1)
    __syncthreads();

    // gx for t=0: wave0 lanes 0..7 hold (gate=lane>>1, unit=lane&1).
    float gxv = 0.f;
    if (w == 0 && lane < 8)
        gxv = gx[(size_t)(lane >> 1) * HDIM + u0 + (lane & 1)];

    for (int t = 0; t < TSEQ; ++t) {
        // ---- dots: wave w computes gate w for its 2 units ----
        float4 hv[4];
#pragma unroll
        for (int j = 0; j < 4; ++j)
            hv[j] = *(const float4*)&sh_h[256 * j + 4 * lane];
#pragma unroll
        for (int u = 0; u < UNITS; ++u) {
            const float* Wr = shW[w * UNITS + u];
            float acc = 0.f;
#pragma unroll
            for (int j = 0; j < 4; ++j) {
                float4 wv = *(const float4*)&Wr[256 * j + 4 * lane];
                acc = fmaf(wv.x, hv[j].x, acc);
                acc = fmaf(wv.y, hv[j].y, acc);
                acc = fmaf(wv.z, hv[j].z, acc);
                acc = fmaf(wv.w, hv[j].w, acc);
            }
#pragma unroll
            for (int off = 32; off; off >>= 1)
                acc += __shfl_xor(acc, off, 64);
            if (lane == 0) sh_gate[w][u] = acc;
        }
        __syncthreads();

        // ---- gate nonlinearity + state update: wave0 lanes 0..1 ----
        const float g0 = __shfl(gxv, 0 + (lane & 1), 64);
        const float g1 = __shfl(gxv, 2 + (lane & 1), 64);
        const float g2 = __shfl(gxv, 4 + (lane & 1), 64);
        const float g3 = __shfl(gxv, 6 + (lane & 1), 64);
        if (w == 0 && lane < UNITS) {
            const float gi = sh_gate[0][lane] + g0;
            const float gf = sh_gate[1][lane] + g1;
            const float gg = sh_gate[2][lane] + g2;
            const float go = sh_gate[3][lane] + g3;
            const float si = 1.f / (1.f + __expf(-gi));
            const float sf = 1.f / (1.f + __expf(-gf));
            const float tg = tanhf(gg);
            const float so = 1.f / (1.f + __expf(-go));
            c = sf * c + si * tg;
            const float h = so * tanhf(c);
            __hip_atomic_store(&hbuf[(t & 1) * HDIM + u0 + lane], h,
                               __ATOMIC_RELAXED, __HIP_MEMORY_SCOPE_AGENT);
            h_out[(size_t)t * HDIM + u0 + lane] = h;   // consumed by next kernel
        }
        // prefetch next step's gx (overlaps barrier wait)
        if (w == 0 && lane < 8) {
            const int tn = (t + 1 < TSEQ) ? t + 1 : t;
            gxv = gx[(size_t)tn * FOURH + (size_t)(lane >> 1) * HDIM + u0 + (lane & 1)];
        }

        // ---- 3-level monotonic barrier, all relaxed ----
        if (tid == 0) {
            // h stores (same wave, lanes 0..1) must be complete at the
            // coherence point before our arrival becomes visible.
            asm volatile("s_waitcnt vmcnt(0)" ::: "memory");
            const unsigned tgt = (unsigned)(ebase + t + 1);
            const int grp = b >> 3;
            unsigned old = __hip_atomic_fetch_add(&bar[grp * 64], 1u,
                                __ATOMIC_RELAXED, __HIP_MEMORY_SCOPE_AGENT);
            if (old + 1u == 8u * tgt) {
                unsigned m = __hip_atomic_fetch_add(&bar[MID_OFF + (grp >> 3) * 64], 1u,
                                    __ATOMIC_RELAXED, __HIP_MEMORY_SCOPE_AGENT);
                if (m + 1u == 8u * tgt) {
                    unsigned r = __hip_atomic_fetch_add(&bar[ROOT_OFF], 1u,
                                        __ATOMIC_RELAXED, __HIP_MEMORY_SCOPE_AGENT);
                    if (r + 1u == 8u * tgt)
                        __hip_atomic_store(&bar[EPOCH_OFF], tgt,
                                           __ATOMIC_RELAXED, __HIP_MEMORY_SCOPE_AGENT);
                }
            }
            while (__hip_atomic_load(&bar[EPOCH_OFF], __ATOMIC_RELAXED,
                                     __HIP_MEMORY_SCOPE_AGENT) < tgt)
                __builtin_amdgcn_s_sleep(1);
        }
        __syncthreads();

        // ---- restage h for t+1 (8-byte relaxed atomic loads) ----
        if (t + 1 < TSEQ) {
            const unsigned long long* hb =
                (const unsigned long long*)(hbuf + (t & 1) * HDIM);
            unsigned long long q0 = __hip_atomic_load(&hb[2 * tid + 0],
                                        __ATOMIC_RELAXED, __HIP_MEMORY_SCOPE_AGENT);
            unsigned long long q1 = __hip_atomic_load(&hb[2 * tid + 1],
                                        __ATOMIC_RELAXED, __HIP_MEMORY_SCOPE_AGENT);
            ((unsigned long long*)sh_h)[2 * tid + 0] = q0;
            ((unsigned long long*)sh_h)[2 * tid + 1] = q1;
            __syncthreads();
        }
    }
}

// ---------------------------------------------------------------------------
extern "C" void kernel_launch(void* const* d_in, const int* in_sizes, int n_in,
                              void* d_out, int out_size, void* d_ws, size_t ws_size,
                              hipStream_t stream)
{
    (void)in_sizes; (void)n_in; (void)out_size; (void)ws_size;

    const float* x = (const float*)d_in[0];
    const float* W_ih[3] = {(const float*)d_in[1], (const float*)d_in[5], (const float*)d_in[9]};
    const float* W_hh[3] = {(const float*)d_in[2], (const float*)d_in[6], (const float*)d_in[10]};
    const float* b_ih[3] = {(const float*)d_in[3], (const float*)d_in[7], (const float*)d_in[11]};
    const float* b_hh[3] = {(const float*)d_in[4], (const float*)d_in[8], (const float*)d_in[12]};
    const float* fc_w = (const float*)d_in[13];
    const float* fc_b = (const float*)d_in[14];
    float* out = (float*)d_out;

    // ws layout: bar[24KB] | gx[T*4H] | hA[T*H] | hB[T*H] | hbuf[2*H]
    unsigned* bar = (unsigned*)d_ws;
    float* gx   = (float*)d_ws + BAR_BYTES / 4;
    float* hA   = gx + (size_t)TSEQ * FOURH;
    float* hB   = hA + (size_t)TSEQ * HDIM;
    float* hbuf = hB + (size_t)TSEQ * HDIM;

    hipMemsetAsync(bar, 0, BAR_BYTES, stream);

    float* houts[3] = {hA, hB, hA};
    const float* in_seq = x;

    for (int l = 0; l < 3; ++l) {
        dim3 gg(FOURH / 64, TSEQ / 64);
        gemm_bias_kernel<<<gg, 256, 0, stream>>>(in_seq, W_ih[l], b_ih[l], b_hh[l],
                                                 gx, TSEQ, FOURH, HDIM);

        const float* gx_c  = gx;
        const float* whh_c = W_hh[l];
        float* ho          = houts[l];
        float* hb          = hbuf;
        unsigned* bar_c    = bar;
        int ebase          = l * TSEQ;
        void* args[] = {(void*)&gx_c, (void*)&whh_c, (void*)&ho, (void*)&hb,
                        (void*)&bar_c, (void*)&ebase};
        hipLaunchCooperativeKernel((void*)lstm_scan_kernel, dim3(NBLK), dim3(256),
                                   args, 0, stream);
        in_seq = houts[l];
    }

    dim3 gf(NCLS / 64, TSEQ / 64);
    gemm_bias_kernel<<<gf, 256, 0, stream>>>(hA, fc_w, fc_b, nullptr,
                                             out, TSEQ, NCLS, HDIM);
}

// Round 4
// 21650.150 us; speedup vs baseline: 33.2279x; 1.1098x over previous
//
#include <hip/hip_runtime.h>

#define HDIM  1024
#define FOURH 4096
#define TSEQ  2048
#define NCLS  512

#define NBLK  256     // scan blocks
#define UNITS 4       // hidden units per block
#define ROWS  16      // W_hh rows per block (4 gates x UNITS)

// ---------------------------------------------------------------------------
// GEMM: C[M,N] = A[M,K] * B[N,K]^T + bias1[N] (+ bias2[N] if non-null)
// ---------------------------------------------------------------------------
__global__ __launch_bounds__(256) void gemm_bias_kernel(
    const float* __restrict__ A, const float* __restrict__ B,
    const float* __restrict__ bias1, const float* __restrict__ bias2,
    float* __restrict__ C, int M, int N, int K)
{
    __shared__ float As[16][68];
    __shared__ float Bs[16][68];

    const int tid = threadIdx.x;
    const int tx = tid & 15;
    const int ty = tid >> 4;
    const int n0 = blockIdx.x * 64;
    const int m0 = blockIdx.y * 64;
    const int r  = tid >> 2;
    const int kq = tid & 3;

    float acc[4][4];
#pragma unroll
    for (int i = 0; i < 4; ++i)
#pragma unroll
        for (int j = 0; j < 4; ++j) acc[i][j] = 0.f;

    for (int k0 = 0; k0 < K; k0 += 16) {
        float4 va = *(const float4*)&A[(size_t)(m0 + r) * K + k0 + 4 * kq];
        float4 vb = *(const float4*)&B[(size_t)(n0 + r) * K + k0 + 4 * kq];
        As[4 * kq + 0][r] = va.x; As[4 * kq + 1][r] = va.y;
        As[4 * kq + 2][r] = va.z; As[4 * kq + 3][r] = va.w;
        Bs[4 * kq + 0][r] = vb.x; Bs[4 * kq + 1][r] = vb.y;
        Bs[4 * kq + 2][r] = vb.z; Bs[4 * kq + 3][r] = vb.w;
        __syncthreads();
#pragma unroll
        for (int kk = 0; kk < 16; ++kk) {
            float4 a = *(const float4*)&As[kk][4 * ty];
            float4 b = *(const float4*)&Bs[kk][4 * tx];
            acc[0][0] = fmaf(a.x, b.x, acc[0][0]);
            acc[0][1] = fmaf(a.x, b.y, acc[0][1]);
            acc[0][2] = fmaf(a.x, b.z, acc[0][2]);
            acc[0][3] = fmaf(a.x, b.w, acc[0][3]);
            acc[1][0] = fmaf(a.y, b.x, acc[1][0]);
            acc[1][1] = fmaf(a.y, b.y, acc[1][1]);
            acc[1][2] = fmaf(a.y, b.z, acc[1][2]);
            acc[1][3] = fmaf(a.y, b.w, acc[1][3]);
            acc[2][0] = fmaf(a.z, b.x, acc[2][0]);
            acc[2][1] = fmaf(a.z, b.y, acc[2][1]);
            acc[2][2] = fmaf(a.z, b.z, acc[2][2]);
            acc[2][3] = fmaf(a.z, b.w, acc[2][3]);
            acc[3][0] = fmaf(a.w, b.x, acc[3][0]);
            acc[3][1] = fmaf(a.w, b.y, acc[3][1]);
            acc[3][2] = fmaf(a.w, b.z, acc[3][2]);
            acc[3][3] = fmaf(a.w, b.w, acc[3][3]);
        }
        __syncthreads();
    }

    float4 bv = *(const float4*)&bias1[n0 + 4 * tx];
    if (bias2) {
        float4 b2 = *(const float4*)&bias2[n0 + 4 * tx];
        bv.x += b2.x; bv.y += b2.y; bv.z += b2.z; bv.w += b2.w;
    }
#pragma unroll
    for (int i = 0; i < 4; ++i) {
        const int row = m0 + 4 * ty + i;
        float4 o;
        o.x = acc[i][0] + bv.x;
        o.y = acc[i][1] + bv.y;
        o.z = acc[i][2] + bv.z;
        o.w = acc[i][3] + bv.w;
        *(float4*)&C[(size_t)row * N + n0 + 4 * tx] = o;
    }
}

// ---------------------------------------------------------------------------
// Persistent LSTM scan, BARRIER-FREE. 256 blocks x 256 threads, cooperative
// launch (co-residency). Readiness is carried BY the data: each h entry is an
// 8-byte atomic {u32 tag = ebase+t+1, f32 h}. Consumers poll the entries they
// need until the tag matches. All atomics relaxed (no L2 inv/wb anywhere).
//
// Slot-reuse safety (D=2, parity t&1, no barrier): A publishes h(t+2) into
// slot t&1 only after consuming all h(t+1), which requires every block to
// have published h(t+1), which requires every block to have consumed h(t)
// from slot t&1. Max skew < 2 steps, so 2 slots suffice. Tags are monotonic
// across layers, so stale entries never false-match.
// ---------------------------------------------------------------------------
__global__ __launch_bounds__(256) void lstm_scan_kernel(
    const float* __restrict__ gx,              // [TSEQ, 4H] input contrib + biases
    const float* __restrict__ Whh,             // [4H, H]
    float* __restrict__ h_out,                 // [TSEQ, H]
    unsigned long long* __restrict__ hbuf,     // [2][HDIM] {tag,h} entries
    int ebase)                                 // = layer * TSEQ
{
    __shared__ __align__(16) float shW[ROWS][HDIM];   // 64 KB
    __shared__ __align__(16) float sh_h[HDIM];        // 4 KB
    __shared__ float sh_gate[4][UNITS];

    const int tid  = threadIdx.x;
    const int b    = blockIdx.x;
    const int w    = tid >> 6;         // wave 0..3 = gate
    const int lane = tid & 63;
    const int u0   = UNITS * b;        // first hidden unit owned

    // Preload 16 weight rows: row r = gate(r>>2), unit (r&3).
#pragma unroll
    for (int r = 0; r < ROWS; ++r) {
        const int R = (r >> 2) * HDIM + u0 + (r & 3);
        *(float4*)&shW[r][4 * tid] = *(const float4*)&Whh[(size_t)R * HDIM + 4 * tid];
    }
    {
        float4 z; z.x = z.y = z.z = z.w = 0.f;
        *(float4*)&sh_h[4 * tid] = z;                  // h(-1) = 0
    }
    float c = 0.f;                                     // cell state (wave0 lanes 0..3)
    __syncthreads();

    // gx for t=0: wave0 lanes 0..15 hold (gate=lane>>2, unit=lane&3).
    float gxv = 0.f;
    if (w == 0 && lane < 16)
        gxv = gx[(size_t)(lane >> 2) * HDIM + u0 + (lane & 3)];

    for (int t = 0; t < TSEQ; ++t) {
        // ---- dots: wave w computes gate w for its 4 units ----
        float4 hv[4];
#pragma unroll
        for (int j = 0; j < 4; ++j)
            hv[j] = *(const float4*)&sh_h[256 * j + 4 * lane];
        float acc[UNITS];
#pragma unroll
        for (int u = 0; u < UNITS; ++u) {
            const float* Wr = shW[4 * w + u];
            float a = 0.f;
#pragma unroll
            for (int j = 0; j < 4; ++j) {
                float4 wv = *(const float4*)&Wr[256 * j + 4 * lane];
                a = fmaf(wv.x, hv[j].x, a);
                a = fmaf(wv.y, hv[j].y, a);
                a = fmaf(wv.z, hv[j].z, a);
                a = fmaf(wv.w, hv[j].w, a);
            }
            acc[u] = a;
        }
#pragma unroll
        for (int off = 32; off; off >>= 1)
#pragma unroll
            for (int u = 0; u < UNITS; ++u)
                acc[u] += __shfl_xor(acc[u], off, 64);
        if (lane == 0)
#pragma unroll
            for (int u = 0; u < UNITS; ++u) sh_gate[w][u] = acc[u];
        __syncthreads();

        const unsigned tag = (unsigned)(ebase + t + 1);

        // ---- gate nonlinearity + tagged publish: wave0 lanes 0..3 ----
        const int ul = lane & 3;
        const float g0 = __shfl(gxv, ul + 0, 64);
        const float g1 = __shfl(gxv, ul + 4, 64);
        const float g2 = __shfl(gxv, ul + 8, 64);
        const float g3 = __shfl(gxv, ul + 12, 64);
        if (w == 0 && lane < UNITS) {
            const float gi = sh_gate[0][lane] + g0;
            const float gf = sh_gate[1][lane] + g1;
            const float gg = sh_gate[2][lane] + g2;
            const float go = sh_gate[3][lane] + g3;
            const float si = 1.f / (1.f + __expf(-gi));
            const float sf = 1.f / (1.f + __expf(-gf));
            const float tg = tanhf(gg);
            const float so = 1.f / (1.f + __expf(-go));
            c = sf * c + si * tg;
            const float h = so * tanhf(c);
            const unsigned long long pk =
                ((unsigned long long)tag << 32) | (unsigned long long)__float_as_uint(h);
            __hip_atomic_store(&hbuf[(t & 1) * HDIM + u0 + lane], pk,
                               __ATOMIC_RELAXED, __HIP_MEMORY_SCOPE_AGENT);
            h_out[(size_t)t * HDIM + u0 + lane] = h;   // consumed by next kernel
        }
        // prefetch next step's gx (overlaps the poll below)
        if (w == 0 && lane < 16) {
            const int tn = (t + 1 < TSEQ) ? t + 1 : t;
            gxv = gx[(size_t)tn * FOURH + (size_t)(lane >> 2) * HDIM + u0 + (lane & 3)];
        }

        // ---- tagged restage of h(t): poll 4 entries per thread ----
        if (t + 1 < TSEQ) {
            const unsigned long long* hb = hbuf + (t & 1) * HDIM;
            unsigned long long v[4];
            bool got[4] = {false, false, false, false};
            int rem = 4;
            while (rem) {
#pragma unroll
                for (int j = 0; j < 4; ++j) {
                    if (!got[j]) {
                        unsigned long long x = __hip_atomic_load(&hb[4 * tid + j],
                                                   __ATOMIC_RELAXED, __HIP_MEMORY_SCOPE_AGENT);
                        if ((unsigned)(x >> 32) == tag) { v[j] = x; got[j] = true; --rem; }
                    }
                }
                if (rem) __builtin_amdgcn_s_sleep(1);
            }
#pragma unroll
            for (int j = 0; j < 4; ++j)
                sh_h[4 * tid + j] = __uint_as_float((unsigned)v[j]);
            __syncthreads();
        }
    }
}

// ---------------------------------------------------------------------------
extern "C" void kernel_launch(void* const* d_in, const int* in_sizes, int n_in,
                              void* d_out, int out_size, void* d_ws, size_t ws_size,
                              hipStream_t stream)
{
    (void)in_sizes; (void)n_in; (void)out_size; (void)ws_size;

    const float* x = (const float*)d_in[0];
    const float* W_ih[3] = {(const float*)d_in[1], (const float*)d_in[5], (const float*)d_in[9]};
    const float* W_hh[3] = {(const float*)d_in[2], (const float*)d_in[6], (const float*)d_in[10]};
    const float* b_ih[3] = {(const float*)d_in[3], (const float*)d_in[7], (const float*)d_in[11]};
    const float* b_hh[3] = {(const float*)d_in[4], (const float*)d_in[8], (const float*)d_in[12]};
    const float* fc_w = (const float*)d_in[13];
    const float* fc_b = (const float*)d_in[14];
    float* out = (float*)d_out;

    // ws layout (floats): gx[T*4H] | hA[T*H] | hB[T*H] | hbuf[2*H as u64]
    float* gx = (float*)d_ws;
    float* hA = gx + (size_t)TSEQ * FOURH;
    float* hB = hA + (size_t)TSEQ * HDIM;
    unsigned long long* hbuf = (unsigned long long*)(hB + (size_t)TSEQ * HDIM);

    float* houts[3] = {hA, hB, hA};
    const float* in_seq = x;

    for (int l = 0; l < 3; ++l) {
        dim3 gg(FOURH / 64, TSEQ / 64);
        gemm_bias_kernel<<<gg, 256, 0, stream>>>(in_seq, W_ih[l], b_ih[l], b_hh[l],
                                                 gx, TSEQ, FOURH, HDIM);

        const float* gx_c  = gx;
        const float* whh_c = W_hh[l];
        float* ho          = houts[l];
        unsigned long long* hb = hbuf;
        int ebase          = l * TSEQ;
        void* args[] = {(void*)&gx_c, (void*)&whh_c, (void*)&ho, (void*)&hb,
                        (void*)&ebase};
        hipLaunchCooperativeKernel((void*)lstm_scan_kernel, dim3(NBLK), dim3(256),
                                   args, 0, stream);
        in_seq = houts[l];
    }

    dim3 gf(NCLS / 64, TSEQ / 64);
    gemm_bias_kernel<<<gf, 256, 0, stream>>>(hA, fc_w, fc_b, nullptr,
                                             out, TSEQ, NCLS, HDIM);
}